// Round 1
// baseline (967.166 us; speedup 1.0000x reference)
//
#include <hip/hip_runtime.h>

typedef __attribute__((ext_vector_type(8))) _Float16 half8;
typedef __attribute__((ext_vector_type(4))) float f32x4;

__device__ __forceinline__ _Float16 f2h(float f) { return (_Float16)f; }

#define LOG100 4.605170185988091f

// ---------------- K0a: bit-pack mask (0 -> 1, -100 -> 0) ----------------
__global__ void k_mask(const float* __restrict__ mask, unsigned short* __restrict__ mbits) {
  int tid = blockIdx.x * 256 + threadIdx.x;
  if (tid >= 64 * 343 * 22) return;
  int t = tid % 22;
  int rem = tid / 22;
  int i = rem % 343;
  int w = rem / 343;
  const float* mrow = mask + ((size_t)w * 343 + i) * 343;
  unsigned bits = 0;
#pragma unroll
  for (int jj = 0; jj < 16; jj++) {
    int col = t * 16 + jj;
    if (col < 343 && mrow[col] > -50.f) bits |= (1u << jj);
  }
  mbits[((size_t)w * 343 + i) * 24 + t] = (unsigned short)bits;
}

// ---------------- K0b: rel-pos bias gather -> fp16 [3][343][344] ----------------
__global__ void k_bias(const int* __restrict__ rpi, const float* __restrict__ table,
                       _Float16* __restrict__ bias_ws) {
  int tid = blockIdx.x * 256 + threadIdx.x;
  if (tid >= 117649) return;
  int i = tid / 343, j = tid - (tid / 343) * 343;
  int r = rpi[tid];
#pragma unroll
  for (int h = 0; h < 3; h++) {
    bias_ws[((size_t)h * 343 + i) * 344 + j] = f2h(table[r * 3 + h]);
  }
}

// ---------------- K1: qkv = x @ Wqkv^T + b; normalize q,k; fold scale into q ----------------
// grid 686 x 1024: block = 256 rows, wave = 16-row m-tile. W in LDS fp16 [288][104].
__global__ __launch_bounds__(1024, 1) void k_qkv(
    const float* __restrict__ x, const float* __restrict__ Wqkv,
    const float* __restrict__ bqkv, const float* __restrict__ ls,
    _Float16* __restrict__ q_ws, _Float16* __restrict__ k_ws, _Float16* __restrict__ v_ws) {
  __shared__ alignas(16) _Float16 Wl[288 * 104];
  const int tid = threadIdx.x;
  for (int i = tid; i < 6912; i += 1024) {  // 288*96/4 float4 loads
    f32x4 w4 = reinterpret_cast<const f32x4*>(Wqkv)[i];
    int f = i * 4, row = f / 96, col = f - row * 96;
    _Float16* dst = &Wl[row * 104 + col];
    dst[0] = f2h(w4[0]); dst[1] = f2h(w4[1]); dst[2] = f2h(w4[2]); dst[3] = f2h(w4[3]);
  }
  __syncthreads();
  const int lane = tid & 63, wv = tid >> 6;
  const int ln15 = lane & 15, quad = lane >> 4;
  const int rowbase = blockIdx.x * 256 + wv * 16;
  const int arow = rowbase + ln15;

  half8 afr[3];
#pragma unroll
  for (int kt = 0; kt < 3; kt++) {
    const float* xp = x + (size_t)arow * 96 + kt * 32 + quad * 8;
    f32x4 a0 = *reinterpret_cast<const f32x4*>(xp);
    f32x4 a1 = *reinterpret_cast<const f32x4*>(xp + 4);
    half8 a;
    a[0] = f2h(a0[0]); a[1] = f2h(a0[1]); a[2] = f2h(a0[2]); a[3] = f2h(a0[3]);
    a[4] = f2h(a1[0]); a[5] = f2h(a1[1]); a[6] = f2h(a1[2]); a[7] = f2h(a1[3]);
    afr[kt] = a;
  }

  int Bb[4], Nn[4];
#pragma unroll
  for (int rr = 0; rr < 4; rr++) {
    int R = rowbase + quad * 4 + rr;
    Bb[rr] = R / 343;
    Nn[rr] = R - Bb[rr] * 343;
  }

  auto ctile = [&](int nt) -> f32x4 {
    f32x4 c = {0.f, 0.f, 0.f, 0.f};
#pragma unroll
    for (int kt = 0; kt < 3; kt++) {
      half8 b = *reinterpret_cast<const half8*>(&Wl[(nt * 16 + ln15) * 104 + kt * 32 + quad * 8]);
      c = __builtin_amdgcn_mfma_f32_16x16x32_f16(afr[kt], b, c, 0, 0, 0);
    }
    return c;
  };

#pragma unroll
  for (int h = 0; h < 3; h++) {
    float sc = __expf(fminf(ls[h], LOG100));
    // ---- q (channels 32h .. 32h+31 -> tiles 2h, 2h+1), normalized * scale ----
    {
      f32x4 c0 = ctile(2 * h), c1 = ctile(2 * h + 1);
      float b0 = bqkv[32 * h + ln15], b1 = bqkv[32 * h + 16 + ln15];
#pragma unroll
      for (int rr = 0; rr < 4; rr++) { c0[rr] += b0; c1[rr] += b1; }
#pragma unroll
      for (int rr = 0; rr < 4; rr++) {
        float s2 = c0[rr] * c0[rr] + c1[rr] * c1[rr];
        s2 += __shfl_xor(s2, 1); s2 += __shfl_xor(s2, 2);
        s2 += __shfl_xor(s2, 4); s2 += __shfl_xor(s2, 8);
        float inv = sc / fmaxf(sqrtf(s2), 1e-12f);
        size_t base = ((size_t)(Bb[rr] * 3 + h) * 343 + Nn[rr]) * 32;
        q_ws[base + ln15] = f2h(c0[rr] * inv);
        q_ws[base + 16 + ln15] = f2h(c1[rr] * inv);
      }
    }
    // ---- k (channels 96+32h -> tiles 6+2h, 7+2h), normalized ----
    {
      f32x4 c0 = ctile(6 + 2 * h), c1 = ctile(7 + 2 * h);
      float b0 = bqkv[96 + 32 * h + ln15], b1 = bqkv[96 + 32 * h + 16 + ln15];
#pragma unroll
      for (int rr = 0; rr < 4; rr++) { c0[rr] += b0; c1[rr] += b1; }
#pragma unroll
      for (int rr = 0; rr < 4; rr++) {
        float s2 = c0[rr] * c0[rr] + c1[rr] * c1[rr];
        s2 += __shfl_xor(s2, 1); s2 += __shfl_xor(s2, 2);
        s2 += __shfl_xor(s2, 4); s2 += __shfl_xor(s2, 8);
        float inv = 1.0f / fmaxf(sqrtf(s2), 1e-12f);
        size_t base = ((size_t)(Bb[rr] * 3 + h) * 343 + Nn[rr]) * 32;
        k_ws[base + ln15] = f2h(c0[rr] * inv);
        k_ws[base + 16 + ln15] = f2h(c1[rr] * inv);
      }
    }
    // ---- v (channels 192+32h -> tiles 12+2h, 13+2h), raw ----
    {
      f32x4 c0 = ctile(12 + 2 * h), c1 = ctile(13 + 2 * h);
      float b0 = bqkv[192 + 32 * h + ln15], b1 = bqkv[192 + 32 * h + 16 + ln15];
#pragma unroll
      for (int rr = 0; rr < 4; rr++) {
        size_t base = ((size_t)(Bb[rr] * 3 + h) * 343 + Nn[rr]) * 32;
        v_ws[base + ln15] = f2h(c0[rr] + b0);
        v_ws[base + 16 + ln15] = f2h(c1[rr] + b1);
      }
    }
  }
}

// ---------------- K2: attention per (b,h). block=192 (3 waves). ----------------
// S tiles via MFMA (K=32=hd), softmax in regs, P->LDS roundtrip, PV via MFMA with V^T in LDS.
__global__ __launch_bounds__(192, 1) void k_attn(
    const _Float16* __restrict__ q_ws, const _Float16* __restrict__ k_ws,
    const _Float16* __restrict__ v_ws, const _Float16* __restrict__ bias_ws,
    const unsigned short* __restrict__ mbits, _Float16* __restrict__ a_ws) {
  __shared__ alignas(16) _Float16 vt[32 * 360];     // V^T: [d][token], stride 360
  __shared__ alignas(16) _Float16 pl[3][16 * 360];  // per-wave P scratch [query][token]
  const int blk = blockIdx.x;
  const int b = blk / 3, h = blk - b * 3, w = b & 63;
  const size_t slice = (size_t)(b * 3 + h) * 343 * 32;
  const _Float16* qb = q_ws + slice;
  const _Float16* kb = k_ws + slice;
  const _Float16* vb = v_ws + slice;
  const int tid = threadIdx.x, lane = tid & 63, wv = tid >> 6;
  const int ln15 = lane & 15, quad = lane >> 4;

  // stage V transposed into LDS
  for (int i = tid; i < 1372; i += 192) {  // 343 rows * 4 chunks of 8
    int n = i >> 2, c4 = i & 3;
    half8 vv = *reinterpret_cast<const half8*>(vb + n * 32 + c4 * 8);
#pragma unroll
    for (int j = 0; j < 8; j++) vt[(c4 * 8 + j) * 360 + n] = vv[j];
  }
  for (int i = tid; i < 544; i += 192) {  // zero token-pad cols 343..359
    int d = i / 17, cc = i - d * 17;
    vt[d * 360 + 343 + cc] = (_Float16)0.f;
  }
  __syncthreads();

  _Float16* pw = pl[wv];
  const _Float16* bias_h = bias_ws + (size_t)h * 343 * 344;
  const unsigned short* mbp = mbits + (size_t)w * 343 * 24;

#pragma unroll 1
  for (int qt = wv; qt < 22; qt += 3) {
    const int qbase = qt * 16;
    half8 aq = *reinterpret_cast<const half8*>(qb + (qbase + ln15) * 32 + quad * 8);
    f32x4 c[22];
#pragma unroll
    for (int kt = 0; kt < 22; kt++) {
      half8 bk = *reinterpret_cast<const half8*>(kb + (kt * 16 + ln15) * 32 + quad * 8);
      f32x4 z = {0.f, 0.f, 0.f, 0.f};
      c[kt] = __builtin_amdgcn_mfma_f32_16x16x32_f16(aq, bk, z, 0, 0, 0);
    }
    float lsum[4];
#pragma unroll
    for (int rr = 0; rr < 4; rr++) {
      const int R = qbase + quad * 4 + rr;
      const bool vrow = (R < 343);
      float m = -1e30f;
#pragma unroll
      for (int kt = 0; kt < 22; kt++) {
        const int col = kt * 16 + ln15;
        float s;
        if (vrow && col < 343) {
          float bia = (float)bias_h[R * 344 + col];
          unsigned mv = mbp[R * 24 + kt];
          s = c[kt][rr] + bia + (((mv >> ln15) & 1u) ? 0.0f : -100.0f);
        } else {
          s = -1e30f;
        }
        c[kt][rr] = s;
        m = fmaxf(m, s);
      }
      m = fmaxf(m, __shfl_xor(m, 1)); m = fmaxf(m, __shfl_xor(m, 2));
      m = fmaxf(m, __shfl_xor(m, 4)); m = fmaxf(m, __shfl_xor(m, 8));
      float sum = 0.f;
#pragma unroll
      for (int kt = 0; kt < 22; kt++) {
        float p = __expf(c[kt][rr] - m);
        c[kt][rr] = p;
        sum += p;
      }
      sum += __shfl_xor(sum, 1); sum += __shfl_xor(sum, 2);
      sum += __shfl_xor(sum, 4); sum += __shfl_xor(sum, 8);
      lsum[rr] = sum;
#pragma unroll
      for (int kt = 0; kt < 22; kt++) {
        pw[(quad * 4 + rr) * 360 + kt * 16 + ln15] = f2h(c[kt][rr]);
      }
    }
    __threadfence_block();  // drain LDS writes before cross-lane reads (same wave)
    f32x4 o0 = {0.f, 0.f, 0.f, 0.f}, o1 = {0.f, 0.f, 0.f, 0.f};
#pragma unroll
    for (int kc = 0; kc < 11; kc++) {
      half8 pa = *reinterpret_cast<const half8*>(pw + ln15 * 360 + kc * 32 + quad * 8);
      half8 v0 = *reinterpret_cast<const half8*>(&vt[ln15 * 360 + kc * 32 + quad * 8]);
      half8 v1 = *reinterpret_cast<const half8*>(&vt[(16 + ln15) * 360 + kc * 32 + quad * 8]);
      o0 = __builtin_amdgcn_mfma_f32_16x16x32_f16(pa, v0, o0, 0, 0, 0);
      o1 = __builtin_amdgcn_mfma_f32_16x16x32_f16(pa, v1, o1, 0, 0, 0);
    }
#pragma unroll
    for (int rr = 0; rr < 4; rr++) {
      const int R = qbase + quad * 4 + rr;
      if (R < 343) {
        float inv = 1.0f / lsum[rr];
        size_t obase = ((size_t)b * 343 + R) * 96 + h * 32;
        a_ws[obase + ln15] = f2h(o0[rr] * inv);
        a_ws[obase + 16 + ln15] = f2h(o1[rr] * inv);
      }
    }
  }
}

// ---------------- K3: out = attn @ Wproj^T + bproj (fp32 out) ----------------
__global__ __launch_bounds__(1024, 1) void k_proj(
    const _Float16* __restrict__ a_ws, const float* __restrict__ Wproj,
    const float* __restrict__ bproj, float* __restrict__ out) {
  __shared__ alignas(16) _Float16 Wl[96 * 104];
  const int tid = threadIdx.x;
  for (int i = tid; i < 2304; i += 1024) {  // 96*96/4
    f32x4 w4 = reinterpret_cast<const f32x4*>(Wproj)[i];
    int f = i * 4, row = f / 96, col = f - row * 96;
    _Float16* dst = &Wl[row * 104 + col];
    dst[0] = f2h(w4[0]); dst[1] = f2h(w4[1]); dst[2] = f2h(w4[2]); dst[3] = f2h(w4[3]);
  }
  __syncthreads();
  const int lane = tid & 63, wv = tid >> 6;
  const int ln15 = lane & 15, quad = lane >> 4;
  const int rowbase = blockIdx.x * 256 + wv * 16;
  half8 afr[3];
#pragma unroll
  for (int kt = 0; kt < 3; kt++) {
    afr[kt] = *reinterpret_cast<const half8*>(a_ws + (size_t)(rowbase + ln15) * 96 + kt * 32 + quad * 8);
  }
#pragma unroll
  for (int nt = 0; nt < 6; nt++) {
    f32x4 c = {0.f, 0.f, 0.f, 0.f};
#pragma unroll
    for (int kt = 0; kt < 3; kt++) {
      half8 bfr = *reinterpret_cast<const half8*>(&Wl[(nt * 16 + ln15) * 104 + kt * 32 + quad * 8]);
      c = __builtin_amdgcn_mfma_f32_16x16x32_f16(afr[kt], bfr, c, 0, 0, 0);
    }
    float bb = bproj[nt * 16 + ln15];
#pragma unroll
    for (int rr = 0; rr < 4; rr++) {
      int R = rowbase + quad * 4 + rr;
      out[(size_t)R * 96 + nt * 16 + ln15] = c[rr] + bb;
    }
  }
}

// ---------------- launch ----------------
extern "C" void kernel_launch(void* const* d_in, const int* in_sizes, int n_in,
                              void* d_out, int out_size, void* d_ws, size_t ws_size,
                              hipStream_t stream) {
  const float* x     = (const float*)d_in[0];
  const float* mask  = (const float*)d_in[1];
  const float* Wqkv  = (const float*)d_in[2];
  const float* bqkv  = (const float*)d_in[3];
  const float* Wproj = (const float*)d_in[4];
  const float* bproj = (const float*)d_in[5];
  const float* ls    = (const float*)d_in[6];
  const float* btab  = (const float*)d_in[7];
  const int*   rpi   = (const int*)d_in[8];
  float* out = (float*)d_out;

  char* ws = (char*)d_ws;
  // 512*3*343*32 fp16 = 33,718,272 B each
  _Float16* q_ws = (_Float16*)(ws);
  _Float16* k_ws = (_Float16*)(ws + 33718272);
  _Float16* v_ws = (_Float16*)(ws + 67436544);
  _Float16* a_ws = (_Float16*)(ws + 101154816);           // 512*343*96 fp16
  _Float16* bias_ws = (_Float16*)(ws + 134873088);        // 3*343*344 fp16 = 707,952 B
  unsigned short* mbits = (unsigned short*)(ws + 135581056);  // 64*343*24 u16 = 1,053,696 B

  hipLaunchKernelGGL(k_mask, dim3((64 * 343 * 22 + 255) / 256), dim3(256), 0, stream, mask, mbits);
  hipLaunchKernelGGL(k_bias, dim3((117649 + 255) / 256), dim3(256), 0, stream, rpi, btab, bias_ws);
  hipLaunchKernelGGL(k_qkv, dim3(686), dim3(1024), 0, stream, x, Wqkv, bqkv, ls, q_ws, k_ws, v_ws);
  hipLaunchKernelGGL(k_attn, dim3(1536), dim3(192), 0, stream, q_ws, k_ws, v_ws, bias_ws, mbits, a_ws);
  hipLaunchKernelGGL(k_proj, dim3(686), dim3(1024), 0, stream, a_ws, Wproj, bproj, out);
}

// Round 2
// 543.146 us; speedup vs baseline: 1.7807x; 1.7807x over previous
//
#include <hip/hip_runtime.h>

typedef __attribute__((ext_vector_type(8))) _Float16 half8;
typedef __attribute__((ext_vector_type(4))) _Float16 half4;
typedef __attribute__((ext_vector_type(4))) float f32x4;

__device__ __forceinline__ _Float16 f2h(float f) { return (_Float16)f; }

#define LOG100 4.605170185988091f
#define NEGBIG -30000.0f

// ---------------- K0a: mask bits in MFMA-fragment layout ----------------
// mb[w][qt][kt][lane] u8, bit rr = allowed(R=qt*16+quad*4+rr, col=kt*16+ln15)
__global__ void k_maskb(const float* __restrict__ mask, unsigned char* __restrict__ mb) {
  int tid = blockIdx.x * 256 + threadIdx.x;
  if (tid >= 64 * 484 * 64) return;
  int lane = tid & 63, idx = tid >> 6;
  int kt = idx % 22, t2 = idx / 22;
  int qt = t2 % 22, w = t2 / 22;
  int col = kt * 16 + (lane & 15), quad = lane >> 4;
  unsigned bits = 0;
#pragma unroll
  for (int rr = 0; rr < 4; rr++) {
    int R = qt * 16 + quad * 4 + rr;
    bool pass = true;
    if (R < 343 && col < 343) pass = mask[((size_t)w * 343 + R) * 343 + col] > -50.f;
    bits |= (pass ? 1u : 0u) << rr;
  }
  mb[tid] = (unsigned char)bits;
}

// ---------------- K0b: rel-pos bias in MFMA-fragment layout (half4 per lane) ----
// bf[h][qt][kt][lane][rr]; invalid (R>=343 || col>=343) -> -30000
__global__ void k_biasf(const int* __restrict__ rpi, const float* __restrict__ table,
                        _Float16* __restrict__ bf) {
  int tid = blockIdx.x * 256 + threadIdx.x;
  if (tid >= 3 * 484 * 64) return;
  int lane = tid & 63, idx = tid >> 6;
  int kt = idx % 22, t2 = idx / 22;
  int qt = t2 % 22, h = t2 / 22;
  int col = kt * 16 + (lane & 15), quad = lane >> 4;
  half4 o;
#pragma unroll
  for (int rr = 0; rr < 4; rr++) {
    int R = qt * 16 + quad * 4 + rr;
    float b = (R < 343 && col < 343) ? table[rpi[R * 343 + col] * 3 + h] : NEGBIG;
    o[rr] = f2h(b);
  }
  reinterpret_cast<half4*>(bf)[tid] = o;
}

// ---------------- K1: qkv = x @ Wqkv^T + b; normalize q,k; fold scale into q ----
__global__ __launch_bounds__(1024, 1) void k_qkv(
    const float* __restrict__ x, const float* __restrict__ Wqkv,
    const float* __restrict__ bqkv, const float* __restrict__ ls,
    _Float16* __restrict__ q_ws, _Float16* __restrict__ k_ws, _Float16* __restrict__ v_ws) {
  __shared__ alignas(16) _Float16 Wl[288 * 104];
  const int tid = threadIdx.x;
  for (int i = tid; i < 6912; i += 1024) {
    f32x4 w4 = reinterpret_cast<const f32x4*>(Wqkv)[i];
    int f = i * 4, row = f / 96, col = f - row * 96;
    _Float16* dst = &Wl[row * 104 + col];
    dst[0] = f2h(w4[0]); dst[1] = f2h(w4[1]); dst[2] = f2h(w4[2]); dst[3] = f2h(w4[3]);
  }
  __syncthreads();
  const int lane = tid & 63, wv = tid >> 6;
  const int ln15 = lane & 15, quad = lane >> 4;
  const int rowbase = blockIdx.x * 256 + wv * 16;
  const int arow = rowbase + ln15;

  half8 afr[3];
#pragma unroll
  for (int kt = 0; kt < 3; kt++) {
    const float* xp = x + (size_t)arow * 96 + kt * 32 + quad * 8;
    f32x4 a0 = *reinterpret_cast<const f32x4*>(xp);
    f32x4 a1 = *reinterpret_cast<const f32x4*>(xp + 4);
    half8 a;
    a[0] = f2h(a0[0]); a[1] = f2h(a0[1]); a[2] = f2h(a0[2]); a[3] = f2h(a0[3]);
    a[4] = f2h(a1[0]); a[5] = f2h(a1[1]); a[6] = f2h(a1[2]); a[7] = f2h(a1[3]);
    afr[kt] = a;
  }

  int Bb[4], Nn[4];
#pragma unroll
  for (int rr = 0; rr < 4; rr++) {
    int R = rowbase + quad * 4 + rr;
    Bb[rr] = R / 343;
    Nn[rr] = R - Bb[rr] * 343;
  }

  auto ctile = [&](int nt) -> f32x4 {
    f32x4 c = {0.f, 0.f, 0.f, 0.f};
#pragma unroll
    for (int kt = 0; kt < 3; kt++) {
      half8 b = *reinterpret_cast<const half8*>(&Wl[(nt * 16 + ln15) * 104 + kt * 32 + quad * 8]);
      c = __builtin_amdgcn_mfma_f32_16x16x32_f16(afr[kt], b, c, 0, 0, 0);
    }
    return c;
  };

#pragma unroll
  for (int h = 0; h < 3; h++) {
    float sc = __expf(fminf(ls[h], LOG100));
    {
      f32x4 c0 = ctile(2 * h), c1 = ctile(2 * h + 1);
      float b0 = bqkv[32 * h + ln15], b1 = bqkv[32 * h + 16 + ln15];
#pragma unroll
      for (int rr = 0; rr < 4; rr++) { c0[rr] += b0; c1[rr] += b1; }
#pragma unroll
      for (int rr = 0; rr < 4; rr++) {
        float s2 = c0[rr] * c0[rr] + c1[rr] * c1[rr];
        s2 += __shfl_xor(s2, 1); s2 += __shfl_xor(s2, 2);
        s2 += __shfl_xor(s2, 4); s2 += __shfl_xor(s2, 8);
        float inv = sc / fmaxf(sqrtf(s2), 1e-12f);
        size_t base = ((size_t)(Bb[rr] * 3 + h) * 343 + Nn[rr]) * 32;
        q_ws[base + ln15] = f2h(c0[rr] * inv);
        q_ws[base + 16 + ln15] = f2h(c1[rr] * inv);
      }
    }
    {
      f32x4 c0 = ctile(6 + 2 * h), c1 = ctile(7 + 2 * h);
      float b0 = bqkv[96 + 32 * h + ln15], b1 = bqkv[96 + 32 * h + 16 + ln15];
#pragma unroll
      for (int rr = 0; rr < 4; rr++) { c0[rr] += b0; c1[rr] += b1; }
#pragma unroll
      for (int rr = 0; rr < 4; rr++) {
        float s2 = c0[rr] * c0[rr] + c1[rr] * c1[rr];
        s2 += __shfl_xor(s2, 1); s2 += __shfl_xor(s2, 2);
        s2 += __shfl_xor(s2, 4); s2 += __shfl_xor(s2, 8);
        float inv = 1.0f / fmaxf(sqrtf(s2), 1e-12f);
        size_t base = ((size_t)(Bb[rr] * 3 + h) * 343 + Nn[rr]) * 32;
        k_ws[base + ln15] = f2h(c0[rr] * inv);
        k_ws[base + 16 + ln15] = f2h(c1[rr] * inv);
      }
    }
    {
      f32x4 c0 = ctile(12 + 2 * h), c1 = ctile(13 + 2 * h);
      float b0 = bqkv[192 + 32 * h + ln15], b1 = bqkv[192 + 32 * h + 16 + ln15];
#pragma unroll
      for (int rr = 0; rr < 4; rr++) {
        size_t base = ((size_t)(Bb[rr] * 3 + h) * 343 + Nn[rr]) * 32;
        v_ws[base + ln15] = f2h(c0[rr] + b0);
        v_ws[base + 16 + ln15] = f2h(c1[rr] + b1);
      }
    }
  }
}

// ---------------- K2: attention per (b,h). 384 threads (6 waves). ----------------
// K staged in LDS once/block; bias+mask in fragment layout; PV chunked thru tiny P buf.
#define KSTR 40
#define VSTR 352
#define PSTR 40
__global__ __launch_bounds__(384, 3) void k_attn(
    const _Float16* __restrict__ q_ws, const _Float16* __restrict__ k_ws,
    const _Float16* __restrict__ v_ws, const half4* __restrict__ bfrag,
    const unsigned char* __restrict__ mb, _Float16* __restrict__ a_ws) {
  __shared__ alignas(16) _Float16 Kl[344 * KSTR];   // 27520 B
  __shared__ alignas(16) _Float16 Vt[32 * VSTR];    // 22528 B
  __shared__ alignas(16) _Float16 Pl[6][16 * PSTR]; // 7680 B
  const int blk = blockIdx.x;
  const int b = blk / 3, h = blk - b * 3, w = b & 63;
  const size_t slice = (size_t)(b * 3 + h) * 343 * 32;
  const _Float16* qb = q_ws + slice;
  const _Float16* kb = k_ws + slice;
  const _Float16* vb = v_ws + slice;
  const int tid = threadIdx.x, lane = tid & 63, wv = tid >> 6;
  const int ln15 = lane & 15, quad = lane >> 4;

  // stage K rows (row 343 = zeros, clamp target for kt=21 pad lanes)
  for (int i = tid; i < 344 * 4; i += 384) {
    int t = i >> 2, c4 = i & 3;
    half8 kv;
    if (t < 343) kv = *reinterpret_cast<const half8*>(kb + t * 32 + c4 * 8);
    else kv = (half8)(_Float16)0.f;
    *reinterpret_cast<half8*>(&Kl[t * KSTR + c4 * 8]) = kv;
  }
  // stage V transposed
  for (int i = tid; i < 1372; i += 384) {
    int n = i >> 2, c4 = i & 3;
    half8 vv = *reinterpret_cast<const half8*>(vb + n * 32 + c4 * 8);
#pragma unroll
    for (int j = 0; j < 8; j++) Vt[(c4 * 8 + j) * VSTR + n] = vv[j];
  }
  for (int i = tid; i < 288; i += 384) {  // zero token-pad cols 343..351
    int d = i / 9, cc = i - d * 9;
    Vt[d * VSTR + 343 + cc] = (_Float16)0.f;
  }
  __syncthreads();

  _Float16* Pw = Pl[wv];
  const half4* bfh = bfrag + (size_t)h * 484 * 64;
  const unsigned char* mbw = mb + (size_t)w * 484 * 64;

#pragma unroll 1
  for (int qt = wv; qt < 22; qt += 6) {
    const int qbase = qt * 16;
    half8 aq = *reinterpret_cast<const half8*>(qb + (qbase + ln15) * 32 + quad * 8);
    f32x4 c[22];
    // S = q.K^T from LDS
#pragma unroll
    for (int kt = 0; kt < 22; kt++) {
      int r = kt * 16 + ln15;
      r = (r > 343) ? 343 : r;
      half8 bk = *reinterpret_cast<const half8*>(&Kl[r * KSTR + quad * 8]);
      f32x4 z = {0.f, 0.f, 0.f, 0.f};
      c[kt] = __builtin_amdgcn_mfma_f32_16x16x32_f16(aq, bk, z, 0, 0, 0);
    }
    // + bias (+ -30000 at pads) + mask
#pragma unroll
    for (int kt = 0; kt < 22; kt++) {
      half4 b4 = bfh[(qt * 22 + kt) * 64 + lane];
      unsigned mv = mbw[(qt * 22 + kt) * 64 + lane];
#pragma unroll
      for (int rr = 0; rr < 4; rr++) {
        c[kt][rr] += (float)b4[rr] + (((mv >> rr) & 1u) ? 0.f : -100.f);
      }
    }
    // softmax (two-pass, rows = quad*4+rr, cols across kt*16+ln15)
    float lsum[4];
#pragma unroll
    for (int rr = 0; rr < 4; rr++) {
      float m = -1e30f;
#pragma unroll
      for (int kt = 0; kt < 22; kt++) m = fmaxf(m, c[kt][rr]);
      m = fmaxf(m, __shfl_xor(m, 1)); m = fmaxf(m, __shfl_xor(m, 2));
      m = fmaxf(m, __shfl_xor(m, 4)); m = fmaxf(m, __shfl_xor(m, 8));
      float sum = 0.f;
#pragma unroll
      for (int kt = 0; kt < 22; kt++) {
        float p = __expf(c[kt][rr] - m);
        c[kt][rr] = p;
        sum += p;
      }
      sum += __shfl_xor(sum, 1); sum += __shfl_xor(sum, 2);
      sum += __shfl_xor(sum, 4); sum += __shfl_xor(sum, 8);
      lsum[rr] = sum;
    }
    // PV in 32-token chunks through per-wave P buffer
    f32x4 o0 = {0.f, 0.f, 0.f, 0.f}, o1 = {0.f, 0.f, 0.f, 0.f};
#pragma unroll 1
    for (int kc = 0; kc < 11; kc++) {
#pragma unroll
      for (int j = 0; j < 2; j++) {
        int kt = kc * 2 + j;
#pragma unroll
        for (int rr = 0; rr < 4; rr++) {
          Pw[(quad * 4 + rr) * PSTR + j * 16 + ln15] = f2h(c[kt][rr]);
        }
      }
      __threadfence_block();
      half8 pa = *reinterpret_cast<const half8*>(Pw + ln15 * PSTR + quad * 8);
      half8 v0 = *reinterpret_cast<const half8*>(&Vt[ln15 * VSTR + kc * 32 + quad * 8]);
      half8 v1 = *reinterpret_cast<const half8*>(&Vt[(16 + ln15) * VSTR + kc * 32 + quad * 8]);
      o0 = __builtin_amdgcn_mfma_f32_16x16x32_f16(pa, v0, o0, 0, 0, 0);
      o1 = __builtin_amdgcn_mfma_f32_16x16x32_f16(pa, v1, o1, 0, 0, 0);
      __threadfence_block();
    }
#pragma unroll
    for (int rr = 0; rr < 4; rr++) {
      const int R = qbase + quad * 4 + rr;
      if (R < 343) {
        float inv = 1.0f / lsum[rr];
        size_t obase = ((size_t)b * 343 + R) * 96 + h * 32;
        a_ws[obase + ln15] = f2h(o0[rr] * inv);
        a_ws[obase + 16 + ln15] = f2h(o1[rr] * inv);
      }
    }
  }
}

// ---------------- K3: out = attn @ Wproj^T + bproj (fp32 out) ----------------
__global__ __launch_bounds__(1024, 1) void k_proj(
    const _Float16* __restrict__ a_ws, const float* __restrict__ Wproj,
    const float* __restrict__ bproj, float* __restrict__ out) {
  __shared__ alignas(16) _Float16 Wl[96 * 104];
  const int tid = threadIdx.x;
  for (int i = tid; i < 2304; i += 1024) {
    f32x4 w4 = reinterpret_cast<const f32x4*>(Wproj)[i];
    int f = i * 4, row = f / 96, col = f - row * 96;
    _Float16* dst = &Wl[row * 104 + col];
    dst[0] = f2h(w4[0]); dst[1] = f2h(w4[1]); dst[2] = f2h(w4[2]); dst[3] = f2h(w4[3]);
  }
  __syncthreads();
  const int lane = tid & 63, wv = tid >> 6;
  const int ln15 = lane & 15, quad = lane >> 4;
  const int rowbase = blockIdx.x * 256 + wv * 16;
  half8 afr[3];
#pragma unroll
  for (int kt = 0; kt < 3; kt++) {
    afr[kt] = *reinterpret_cast<const half8*>(a_ws + (size_t)(rowbase + ln15) * 96 + kt * 32 + quad * 8);
  }
#pragma unroll
  for (int nt = 0; nt < 6; nt++) {
    f32x4 c = {0.f, 0.f, 0.f, 0.f};
#pragma unroll
    for (int kt = 0; kt < 3; kt++) {
      half8 bfr = *reinterpret_cast<const half8*>(&Wl[(nt * 16 + ln15) * 104 + kt * 32 + quad * 8]);
      c = __builtin_amdgcn_mfma_f32_16x16x32_f16(afr[kt], bfr, c, 0, 0, 0);
    }
    float bb = bproj[nt * 16 + ln15];
#pragma unroll
    for (int rr = 0; rr < 4; rr++) {
      int R = rowbase + quad * 4 + rr;
      out[(size_t)R * 96 + nt * 16 + ln15] = c[rr] + bb;
    }
  }
}

// ---------------- launch ----------------
extern "C" void kernel_launch(void* const* d_in, const int* in_sizes, int n_in,
                              void* d_out, int out_size, void* d_ws, size_t ws_size,
                              hipStream_t stream) {
  const float* x     = (const float*)d_in[0];
  const float* mask  = (const float*)d_in[1];
  const float* Wqkv  = (const float*)d_in[2];
  const float* bqkv  = (const float*)d_in[3];
  const float* Wproj = (const float*)d_in[4];
  const float* bproj = (const float*)d_in[5];
  const float* ls    = (const float*)d_in[6];
  const float* btab  = (const float*)d_in[7];
  const int*   rpi   = (const int*)d_in[8];
  float* out = (float*)d_out;

  char* ws = (char*)d_ws;
  _Float16* q_ws = (_Float16*)(ws);
  _Float16* k_ws = (_Float16*)(ws + 33718272);
  _Float16* v_ws = (_Float16*)(ws + 67436544);
  _Float16* a_ws = (_Float16*)(ws + 101154816);
  _Float16* bfrag = (_Float16*)(ws + 134873088);          // 3*484*64*4 fp16 = 743,424 B
  unsigned char* mbf = (unsigned char*)(ws + 135616512);  // 64*484*64 u8 = 1,982,464 B

  hipLaunchKernelGGL(k_maskb, dim3((64 * 484 * 64 + 255) / 256), dim3(256), 0, stream, mask, mbf);
  hipLaunchKernelGGL(k_biasf, dim3((3 * 484 * 64 + 255) / 256), dim3(256), 0, stream, rpi, btab, bfrag);
  hipLaunchKernelGGL(k_qkv, dim3(686), dim3(1024), 0, stream, x, Wqkv, bqkv, ls, q_ws, k_ws, v_ws);
  hipLaunchKernelGGL(k_attn, dim3(1536), dim3(384), 0, stream, q_ws, k_ws, v_ws,
                     (const half4*)bfrag, mbf, a_ws);
  hipLaunchKernelGGL(k_proj, dim3(686), dim3(1024), 0, stream, a_ws, Wproj, bproj, out);
}